// Round 14
// baseline (234.299 us; speedup 1.0000x reference)
//
#include <hip/hip_runtime.h>
#include <hip/hip_bf16.h>
#include <math.h>

// Problem constants: B=16,C=16,T=160,H=36,W=36, S=1,R=1,STEPS=4
#define BS_   16
#define D_    160
#define N_    20736
#define P2_   447
#define RP_   448        // padded R row stride (16B-aligned float4 rows)
#define EPS_  1e-6f

// Gram geometry: 27 chunk-blocks x 16 batches; 768 cols = 24 k-chunks of 32 cols.
#define KC_   27
#define NBC_  768

// Workspace layout (float offsets), ~2.2 MB
#define OFF_R    0                        // rbfs   [160][448] (col 447 = 0 pad)
#define OFF_RT   (OFF_R  + D_*RP_)        // (unused since R5)
#define OFF_G    (OFF_RT + P2_*D_)        // G      [16][160][160]
#define OFF_BPF  (OFF_G  + BS_*D_*D_)     // bp_f   [16][160]
#define OFF_SF   (OFF_BPF + BS_*D_)       // 1/s_f  [16]
#define WS_FLOATS (OFF_SF + BS_)

typedef __attribute__((ext_vector_type(8))) short short8;   // 8 bf16 (4 VGPRs)
typedef __attribute__((ext_vector_type(4))) float f32x4;

// Async global->LDS 16B copy: lane's 16B from per-lane global addr lands at
// (wave-uniform LDS base) + lane*16.
#define GLOAD_LDS(gp, lp)                                                     \
  __builtin_amdgcn_global_load_lds(                                           \
      (const __attribute__((address_space(1))) void*)(gp),                    \
      (__attribute__((address_space(3))) void*)(lp), 16, 0, 0)

// Counted-wait barrier (T3/T4): own ds_reads drained, all but newest N vmem
// ops complete, then raw s_barrier (no compiler-forced vmcnt(0) drain).
#define WAITB(n)                                                              \
  do {                                                                        \
    asm volatile("s_waitcnt lgkmcnt(0) vmcnt(" #n ")" ::: "memory");          \
    __builtin_amdgcn_s_barrier();                                             \
  } while (0)

// 55 symmetric block-pairs (I<=J) over 10 row-blocks of 16
constexpr int PI_[55] = {0,0,0,0,0,0,0,0,0,0, 1,1,1,1,1,1,1,1,1, 2,2,2,2,2,2,2,2,
                         3,3,3,3,3,3,3, 4,4,4,4,4,4, 5,5,5,5,5, 6,6,6,6, 7,7,7, 8,8, 9};
constexpr int PJ_[55] = {0,1,2,3,4,5,6,7,8,9, 1,2,3,4,5,6,7,8,9, 2,3,4,5,6,7,8,9,
                         3,4,5,6,7,8,9, 4,5,6,7,8,9, 5,6,7,8,9, 6,7,8,9, 7,8,9, 8,9, 9};

__device__ __forceinline__ float wave_sum(float v) {
#pragma unroll
  for (int m = 1; m < 64; m <<= 1) v += __shfl_xor(v, m, 64);
  return v;
}

__device__ __forceinline__ short tobf(float f) {
  __hip_bfloat16 h = __float2bfloat16(f);        // RTN-even
  union { __hip_bfloat16 h; short s; } u; u.h = h;
  return u.s;
}

__device__ __forceinline__ float dot4(float4 a, float4 b, float acc) {
  return fmaf(a.x, b.x, fmaf(a.y, b.y, fmaf(a.z, b.z, fmaf(a.w, b.w, acc))));
}

// Async-staged Gram worker. One wave's share of pair-MFMAs over 24 k-chunks
// of 32 columns. f32 tile [160][32] TRIPLE-buffered in LDS (depth-2 prefetch,
// counted vmcnt(5) waits), staged via global_load_lds with PRE-SWIZZLED global
// source; f32->bf16 conversion at fragment-read time. NT partial stores.
template<int P0, int NP>
__device__ __forceinline__ void gram_pipe(const float* __restrict__ xb,
                                          float* __restrict__ b0,
                                          float* __restrict__ b1,
                                          float* __restrict__ b2,
                                          float* __restrict__ pp,
                                          const int w, const int lane) {
  // Staging: group g covers rows 8g..8g+7 (20 groups; wave w issues g=5w..5w+4).
  // Lane l -> row 8g+(l>>3); source unit u = (l&7)^((l>>3)&7);
  // LDS slot = group base + l*16B  == row-major [160][32] with physical unit l&7.
  const int srow = lane >> 3;
  const int suni = (lane & 7) ^ (srow & 7);
  const size_t sgoff = (size_t)srow * N_ + suni * 4;

  // Fragment read: lane wants logical units u0=(l>>4)*2, u0+1 of row 16f+(l&15).
  // Physical p = u ^ (row&7), row&7 == l&7 (16f%8=0): p0 = u0^(l&7), p1 = p0^1.
  const int r15 = lane & 15, r7 = lane & 7;
  const int u0 = (lane >> 4) * 2;
  const int p0 = u0 ^ r7, p1 = p0 ^ 1;

  f32x4 acc[NP];
#pragma unroll
  for (int q = 0; q < NP; ++q) acc[q] = (f32x4)0.f;

  auto ISSUE = [&](int cc, float* buf) {
    const float* xp = xb + cc * 32;
#pragma unroll
    for (int j = 0; j < 5; ++j) {
      const int g = 5 * w + j;
      GLOAD_LDS(xp + (size_t)(8 * g) * N_ + sgoff, buf + g * 256);
    }
  };
  auto COMP = [&](const float* buf) {
    short8 fr[10];
#pragma unroll
    for (int f = 0; f < 10; ++f) {
      const float* rp = buf + (16 * f + r15) * 32;
      float4 a = *(const float4*)(rp + p0 * 4);   // logical floats 0-3 (unit u0)
      float4 b = *(const float4*)(rp + p1 * 4);   // logical floats 4-7 (unit u0+1)
      short8 s;
      s[0] = tobf(a.x); s[1] = tobf(a.y); s[2] = tobf(a.z); s[3] = tobf(a.w);
      s[4] = tobf(b.x); s[5] = tobf(b.y); s[6] = tobf(b.z); s[7] = tobf(b.w);
      fr[f] = s;
    }
#pragma unroll
    for (int q = 0; q < NP; ++q)
      acc[q] = __builtin_amdgcn_mfma_f32_16x16x32_bf16(fr[PI_[P0 + 4 * q]],
                                                       fr[PJ_[P0 + 4 * q]],
                                                       acc[q], 0, 0, 0);
  };

  // Depth-2 pipeline over 24 chunks: iteration c does ISSUE(c+2), COMP(c),
  // then waits vmcnt(5) (chunk c+1 complete, c+2's 5 loads still in flight).
  ISSUE(0, b0); ISSUE(1, b1);
  WAITB(5);                                     // chunk 0 ready
#pragma unroll 1
  for (int c = 0; c < 21; c += 3) {             // c = 0..20 (7 triples)
    ISSUE(c + 2, b2); COMP(b0); WAITB(5);
    ISSUE(c + 3, b0); COMP(b1); WAITB(5);
    ISSUE(c + 4, b1); COMP(b2); WAITB(5);
  }
  ISSUE(23, b2); COMP(b0); WAITB(5);            // c = 21; chunk 22 ready
  COMP(b1);                                     // chunk 22
  WAITB(0);                                     // chunk 23 fully landed
  COMP(b2);                                     // chunk 23

#pragma unroll
  for (int q = 0; q < NP; ++q)
    __builtin_nontemporal_store(
        acc[q], (f32x4*)(pp + (size_t)(P0 + 4 * q) * 256 + lane * 4));
}

// Partial Gram via MFMA with async triple-buffered f32 LDS. Grid (27,16) x 256.
__global__ __launch_bounds__(256) void k_gram(const float* __restrict__ x,
                                              float* __restrict__ outsc) {
  __shared__ float lds[3 * 5120];   // 3 x [160][32] f32 = 60 KB
  const int bs = blockIdx.y, ch = blockIdx.x;
  const int t = threadIdx.x, w = t >> 6, lane = t & 63;
  const float* xb = x + (size_t)bs * D_ * N_ + (size_t)ch * NBC_;
  float* pp = outsc + (size_t)(ch * BS_ + bs) * (55 * 256);
  // Every wave executes the same barrier sequence (divergent roles OK).
  switch (w) {
    case 0:  gram_pipe<0, 14>(xb, lds, lds + 5120, lds + 10240, pp, 0, lane); break;
    case 1:  gram_pipe<1, 14>(xb, lds, lds + 5120, lds + 10240, pp, 1, lane); break;
    case 2:  gram_pipe<2, 14>(xb, lds, lds + 5120, lds + 10240, pp, 2, lane); break;
    default: gram_pipe<3, 13>(xb, lds, lds + 5120, lds + 10240, pp, 3, lane); break;
  }
}

// Reduce 27 partials (nontemporal reads), unscramble C/D layout, mirror.
// Grid (55,16). Also builds the rbfs dictionary R (fused former k_init).
__global__ __launch_bounds__(256) void k_gsum(const float* __restrict__ outsc,
                                              float* __restrict__ ws) {
  const int p = blockIdx.x, bs = blockIdx.y, s = threadIdx.x;
  const float* q = outsc + (size_t)bs * (55 * 256) + (size_t)p * 256 + s;
  float v = 0.f;
#pragma unroll
  for (int c = 0; c < KC_; ++c)
    v += __builtin_nontemporal_load(q + (size_t)c * ((size_t)BS_ * 55 * 256));
  const int l = s >> 2, r = s & 3;
  const int row = (l >> 4) * 4 + r, col = l & 15;
  const int gi = PI_[p] * 16 + row, gj = PJ_[p] * 16 + col;
  float* G = ws + OFF_G + (size_t)bs * (D_ * D_);
  G[gi * D_ + gj] = v;
  G[gj * D_ + gi] = v;

  // ---- fused R init (former k_init): first 280 block-worths cover 160*448 ----
  const int gid = (bs * 55 + p) * 256 + s;
  if (gid < D_ * RP_) {
    const int d = gid / RP_, j = gid % RP_;
    float rv;
    if (j == RP_ - 1) {
      rv = 0.f;                                  // pad column
    } else if (j == P2_ - 1) {
      rv = 1.f;
    } else {
      float sig; int colc;
      if (j < 160)      { sig = 1.f;  colc = j; }
      else if (j < 240) { sig = 2.f;  colc = 2 * (j - 160); }
      else if (j < 320) { sig = 4.f;  colc = 2 * (j - 240); }
      else if (j < 374) { sig = 6.f;  colc = 3 * (j - 320); }
      else if (j < 414) { sig = 8.f;  colc = 4 * (j - 374); }
      else              { sig = 10.f; colc = 5 * (j - 414); }
      float diff = (float)(d - colc);
      rv = expf(diff * diff * (-0.25f / (sig * sig)));
    }
    ws[OFF_R + gid] = rv;
  }
}

// All 4 NMF steps + final bp_f/s_f. One block per batch, 512 threads.
// R5: G cached in LDS (stride 164); phase 3 computes RT rows on the fly.
// R11: phase 1 wave-cooperative. R13: R hoisted to registers (140 VGPR/lane).
// R14 DIAGNOSTIC: launched TWICE (idempotent — reads bases0/R/G unmodified,
// writes only BPF/SF deterministically); dur delta vs R13 = t_iter.
#define GLSTR 164
__global__ __launch_bounds__(512, 2) void k_iter(const float* __restrict__ bases0,
                                                 float* __restrict__ ws) {
  const int bs = blockIdx.x;
  const int t  = threadIdx.x;
  const int w  = t >> 6;
  const int lane = t & 63;
  __shared__ __align__(16) float basl[RP_];
  __shared__ __align__(16) float bpl[D_];
  __shared__ __align__(16) float yl[D_];
  __shared__ float redA[8], redB[8];
  __shared__ __align__(16) float gl[D_ * GLSTR];   // ~105 KB
  if (t < RP_) basl[t] = (t < P2_) ? bases0[bs * P2_ + t] : 0.f;

  // Per-thread phase-3 constants: row t of RT == column t of R.
  float col_t = 0.f, c2_t = 0.f;
  {
    int j = t; float sig = 0.f; int col = 0;
    if (j < 160)      { sig = 1.f;  col = j; }
    else if (j < 240) { sig = 2.f;  col = 2 * (j - 160); }
    else if (j < 320) { sig = 4.f;  col = 2 * (j - 240); }
    else if (j < 374) { sig = 6.f;  col = 3 * (j - 320); }
    else if (j < 414) { sig = 8.f;  col = 4 * (j - 374); }
    else if (j < 446) { sig = 10.f; col = 5 * (j - 414); }
    else              { sig = 0.f;  col = 0; }     // ones column (and inactive)
    col_t = (float)col;
    c2_t  = (sig > 0.f) ? (-0.25f / (sig * sig)) * 1.44269504088896340736f : 0.f;
  }

  // ---- R13: load this wave's R rows into registers (once) ----
  const float* rw = ws + OFF_R + (size_t)(20 * w) * RP_ + lane;
  float rreg[20][7];
#pragma unroll
  for (int rr = 0; rr < 20; ++rr)
#pragma unroll
    for (int c = 0; c < 7; ++c)
      rreg[rr][c] = rw[(size_t)rr * RP_ + 64 * c];

  // Preload G into LDS (overlaps the R register loads above).
  const float* G = ws + OFF_G + (size_t)bs * (D_ * D_);
  for (int i = t; i < D_ * 40; i += 512) {
    const int r = i / 40, k = i - r * 40;
    *(f32x4*)&gl[r * GLSTR + k * 4] = *(const f32x4*)(G + (size_t)r * D_ + k * 4);
  }
  __syncthreads();

  const float4* bpl4 = (const float4*)bpl;

  for (int step = 0; step < 5; ++step) {
    // ---- phase 1: bp = R @ bases (register R, wave-cooperative) ----
    {
      float bl[7];
#pragma unroll
      for (int c = 0; c < 7; ++c) bl[c] = basl[lane + 64 * c];
#pragma unroll
      for (int rr = 0; rr < 20; rr += 4) {
        float p0 = 0.f, p1 = 0.f, p2 = 0.f, p3 = 0.f;
#pragma unroll
        for (int c = 0; c < 7; ++c) {
          p0 = fmaf(rreg[rr][c],     bl[c], p0);
          p1 = fmaf(rreg[rr + 1][c], bl[c], p1);
          p2 = fmaf(rreg[rr + 2][c], bl[c], p2);
          p3 = fmaf(rreg[rr + 3][c], bl[c], p3);
        }
        p0 = wave_sum(p0); p1 = wave_sum(p1);
        p2 = wave_sum(p2); p3 = wave_sum(p3);
        if (lane == 0) {
          bpl[20 * w + rr]     = p0;
          bpl[20 * w + rr + 1] = p1;
          bpl[20 * w + rr + 2] = p2;
          bpl[20 * w + rr + 3] = p3;
        }
      }
    }
    __syncthreads();                       // bpl visible to all
    const float bpv = (t < D_) ? bpl[t] : 0.f;
    { float v = wave_sum(bpv * bpv);
      if ((t & 63) == 0) redA[w] = v; }
    __syncthreads();
    float s = 0.f;
#pragma unroll
    for (int i = 0; i < 8; ++i) s += redA[i];

    if (step == 4) {
      if (t < D_) ws[OFF_BPF + bs * D_ + t] = bpv;
      if (t == 0) ws[OFF_SF + bs] = 1.f / s;
      return;
    }

    // ---- phase 2: y = G @ bp (from LDS) ----
    float yv = 0.f;
    if (t < D_) {
      const float* gr = &gl[t * GLSTR];
#pragma unroll
      for (int k = 0; k < 40; ++k) {
        float4 gv = *(const float4*)(gr + 4 * k);
        yv = dot4(gv, bpl4[k], yv);
      }
      yl[t] = yv;
    }
    { float v = wave_sum((t < D_) ? bpv * yv : 0.f);
      if ((t & 63) == 0) redB[w] = v; }
    __syncthreads();
    float byp = 0.f;
#pragma unroll
    for (int i = 0; i < 8; ++i) byp += redB[i];

    // ---- phase 3: nb/rb = on-the-fly RT row . {y, bp}; bases update ----
    if (t < P2_) {
      float nb = 0.f, rb = 0.f;
#pragma unroll 4
      for (int k = 0; k < 40; ++k) {
        const f32x4 y4 = *(const f32x4*)&yl[4 * k];
        const f32x4 b4 = *(const f32x4*)&bpl[4 * k];
#pragma unroll
        for (int m = 0; m < 4; ++m) {
          const float diff = (float)(4 * k + m) - col_t;
          const float e = exp2f(diff * diff * c2_t);
          nb = fmaf(e, y4[m], nb);
          rb = fmaf(e, b4[m], rb);
        }
      }
      const float c2 = byp / (s * s);
      basl[t] = basl[t] * (nb / s) / (rb * c2 + EPS_);
    }
    __syncthreads();
  }
}

// Pass A: cn[bs][n] = (x^T bp_f)*sf. Pure 212MB read stream. Grid (81,16)x256,
// 4 waves split d (40 rows each), 4KB LDS cross-wave reduce. cn stored into out
// row d=0 as scratch (overwritten with the true row 0 by k_out).
__global__ __launch_bounds__(256) void k_coef(const float* __restrict__ x,
                                              const float* __restrict__ ws,
                                              float* __restrict__ out) {
  __shared__ __align__(16) float bpl[D_];
  __shared__ __align__(16) float nsum[4][256];
  const int bs = blockIdx.y, cb = blockIdx.x;
  const int t = threadIdx.x, w = t >> 6, lane = t & 63;
  const int n0 = cb * 256;                 // 81 blocks * 256 cols = 20736 exactly

  if (t < D_) bpl[t] = ws[OFF_BPF + bs * D_ + t];
  __syncthreads();

  const float* xb = x + (size_t)bs * D_ * N_ + n0 + lane * 4;
  const int d0 = w * 40;
  float4 num = {0.f, 0.f, 0.f, 0.f};
#pragma unroll 8
  for (int k = 0; k < 40; ++k) {
    float4 v = *(const float4*)(xb + (size_t)(d0 + k) * N_);
    const float b = bpl[d0 + k];
    num.x = fmaf(v.x, b, num.x);
    num.y = fmaf(v.y, b, num.y);
    num.z = fmaf(v.z, b, num.z);
    num.w = fmaf(v.w, b, num.w);
  }
  *(float4*)&nsum[w][lane * 4] = num;
  __syncthreads();

  const float sf = ws[OFF_SF + bs];
  out[(size_t)bs * D_ * N_ + n0 + t] =
      (nsum[0][t] + nsum[1][t] + nsum[2][t] + nsum[3][t]) * sf;
}

// Pass B: out[d][n] = bp[d]*cn[n]. Pure 212MB write stream (nontemporal).
// cn read from out row 0 BEFORE a vmcnt(0)+barrier fence, then row 0 is
// overwritten with its true value like every other row.
__global__ __launch_bounds__(256) void k_out(const float* __restrict__ ws,
                                             float* __restrict__ out) {
  __shared__ __align__(16) float bpl[D_];
  const int bs = blockIdx.y, cb = blockIdx.x;
  const int t = threadIdx.x, w = t >> 6, lane = t & 63;
  const int n0 = cb * 256;

  float* ob = out + (size_t)bs * D_ * N_ + n0 + lane * 4;
  const f32x4 cn = *(const f32x4*)ob;      // row-0 scratch read (all 4 waves)
  if (t < D_) bpl[t] = ws[OFF_BPF + bs * D_ + t];
  // Ensure every wave's cn load has COMPLETED before any wave stores row 0.
  asm volatile("s_waitcnt vmcnt(0)" ::: "memory");
  __syncthreads();

  const int d0 = w * 40;
#pragma unroll 8
  for (int k = 0; k < 40; ++k) {
    const float b = bpl[d0 + k];
    f32x4 o;
    o[0] = b * cn[0]; o[1] = b * cn[1]; o[2] = b * cn[2]; o[3] = b * cn[3];
    __builtin_nontemporal_store(o, (f32x4*)(ob + (size_t)(d0 + k) * N_));
  }
}

extern "C" void kernel_launch(void* const* d_in, const int* in_sizes, int n_in,
                              void* d_out, int out_size, void* d_ws, size_t ws_size,
                              hipStream_t stream) {
  const float* x      = (const float*)d_in[0];   // (16,160,20736)
  const float* bases0 = (const float*)d_in[1];   // (16,447,1)
  float* out = (float*)d_out;                    // gram-partial scratch, then final output
  float* ws  = (float*)d_ws;                     // needs WS_FLOATS*4 ≈ 2.2 MB

  k_gram<<<dim3(KC_, BS_), 256, 0, stream>>>(x, out);
  k_gsum<<<dim3(55, BS_), 256, 0, stream>>>(out, ws);   // partials + fused R init
  // R14 DIAGNOSTIC: k_iter launched twice (idempotent). dur_us delta vs the
  // R13 single-launch baseline (180.1 us) measures t_iter directly.
  k_iter<<<BS_, 512, 0, stream>>>(bases0, ws);
  k_iter<<<BS_, 512, 0, stream>>>(bases0, ws);
  k_coef<<<dim3(81, BS_), 256, 0, stream>>>(x, ws, out);
  k_out<<<dim3(81, BS_), 256, 0, stream>>>(ws, out);
}

// Round 15
// 157.712 us; speedup vs baseline: 1.4856x; 1.4856x over previous
//
#include <hip/hip_runtime.h>
#include <hip/hip_bf16.h>
#include <math.h>

// Problem constants: B=16,C=16,T=160,H=36,W=36, S=1,R=1,STEPS=4
#define BS_   16
#define D_    160
#define N_    20736
#define P2_   447
#define RP_   448        // padded R row stride (16B-aligned float4 rows)
#define EPS_  1e-6f

// Gram geometry: 27 chunk-blocks x 16 batches; 768 cols = 24 k-chunks of 32 cols.
#define KC_   27
#define NBC_  768

// Workspace layout (float offsets), ~2.2 MB
#define OFF_R    0                        // rbfs   [160][448] (col 447 = 0 pad)
#define OFF_RT   (OFF_R  + D_*RP_)        // (unused since R5)
#define OFF_G    (OFF_RT + P2_*D_)        // G      [16][160][160]
#define OFF_BPF  (OFF_G  + BS_*D_*D_)     // bp_f   [16][160]
#define OFF_SF   (OFF_BPF + BS_*D_)       // 1/s_f  [16]
#define WS_FLOATS (OFF_SF + BS_)

typedef __attribute__((ext_vector_type(8))) short short8;   // 8 bf16 (4 VGPRs)
typedef __attribute__((ext_vector_type(4))) float f32x4;

// Async global->LDS 16B copy: lane's 16B from per-lane global addr lands at
// (wave-uniform LDS base) + lane*16.
#define GLOAD_LDS(gp, lp)                                                     \
  __builtin_amdgcn_global_load_lds(                                           \
      (const __attribute__((address_space(1))) void*)(gp),                    \
      (__attribute__((address_space(3))) void*)(lp), 16, 0, 0)

// Counted-wait barrier (T3/T4): own ds_reads drained, all but newest N vmem
// ops complete, then raw s_barrier (no compiler-forced vmcnt(0) drain).
#define WAITB(n)                                                              \
  do {                                                                        \
    asm volatile("s_waitcnt lgkmcnt(0) vmcnt(" #n ")" ::: "memory");          \
    __builtin_amdgcn_s_barrier();                                             \
  } while (0)

// 55 symmetric block-pairs (I<=J) over 10 row-blocks of 16
constexpr int PI_[55] = {0,0,0,0,0,0,0,0,0,0, 1,1,1,1,1,1,1,1,1, 2,2,2,2,2,2,2,2,
                         3,3,3,3,3,3,3, 4,4,4,4,4,4, 5,5,5,5,5, 6,6,6,6, 7,7,7, 8,8, 9};
constexpr int PJ_[55] = {0,1,2,3,4,5,6,7,8,9, 1,2,3,4,5,6,7,8,9, 2,3,4,5,6,7,8,9,
                         3,4,5,6,7,8,9, 4,5,6,7,8,9, 5,6,7,8,9, 6,7,8,9, 7,8,9, 8,9, 9};

__device__ __forceinline__ float wave_sum(float v) {
#pragma unroll
  for (int m = 1; m < 64; m <<= 1) v += __shfl_xor(v, m, 64);
  return v;
}

__device__ __forceinline__ short tobf(float f) {
  __hip_bfloat16 h = __float2bfloat16(f);        // RTN-even
  union { __hip_bfloat16 h; short s; } u; u.h = h;
  return u.s;
}

__device__ __forceinline__ float dot4(float4 a, float4 b, float acc) {
  return fmaf(a.x, b.x, fmaf(a.y, b.y, fmaf(a.z, b.z, fmaf(a.w, b.w, acc))));
}

// Async-staged Gram worker. One wave's share of pair-MFMAs over 24 k-chunks
// of 32 columns. f32 tile [160][32] TRIPLE-buffered in LDS (depth-2 prefetch,
// counted vmcnt(5) waits), staged via global_load_lds with PRE-SWIZZLED global
// source; f32->bf16 conversion at fragment-read time. NT partial stores.
template<int P0, int NP>
__device__ __forceinline__ void gram_pipe(const float* __restrict__ xb,
                                          float* __restrict__ b0,
                                          float* __restrict__ b1,
                                          float* __restrict__ b2,
                                          float* __restrict__ pp,
                                          const int w, const int lane) {
  // Staging: group g covers rows 8g..8g+7 (20 groups; wave w issues g=5w..5w+4).
  // Lane l -> row 8g+(l>>3); source unit u = (l&7)^((l>>3)&7);
  // LDS slot = group base + l*16B  == row-major [160][32] with physical unit l&7.
  const int srow = lane >> 3;
  const int suni = (lane & 7) ^ (srow & 7);
  const size_t sgoff = (size_t)srow * N_ + suni * 4;

  // Fragment read: lane wants logical units u0=(l>>4)*2, u0+1 of row 16f+(l&15).
  // Physical p = u ^ (row&7), row&7 == l&7 (16f%8=0): p0 = u0^(l&7), p1 = p0^1.
  const int r15 = lane & 15, r7 = lane & 7;
  const int u0 = (lane >> 4) * 2;
  const int p0 = u0 ^ r7, p1 = p0 ^ 1;

  f32x4 acc[NP];
#pragma unroll
  for (int q = 0; q < NP; ++q) acc[q] = (f32x4)0.f;

  auto ISSUE = [&](int cc, float* buf) {
    const float* xp = xb + cc * 32;
#pragma unroll
    for (int j = 0; j < 5; ++j) {
      const int g = 5 * w + j;
      GLOAD_LDS(xp + (size_t)(8 * g) * N_ + sgoff, buf + g * 256);
    }
  };
  auto COMP = [&](const float* buf) {
    short8 fr[10];
#pragma unroll
    for (int f = 0; f < 10; ++f) {
      const float* rp = buf + (16 * f + r15) * 32;
      float4 a = *(const float4*)(rp + p0 * 4);   // logical floats 0-3 (unit u0)
      float4 b = *(const float4*)(rp + p1 * 4);   // logical floats 4-7 (unit u0+1)
      short8 s;
      s[0] = tobf(a.x); s[1] = tobf(a.y); s[2] = tobf(a.z); s[3] = tobf(a.w);
      s[4] = tobf(b.x); s[5] = tobf(b.y); s[6] = tobf(b.z); s[7] = tobf(b.w);
      fr[f] = s;
    }
#pragma unroll
    for (int q = 0; q < NP; ++q)
      acc[q] = __builtin_amdgcn_mfma_f32_16x16x32_bf16(fr[PI_[P0 + 4 * q]],
                                                       fr[PJ_[P0 + 4 * q]],
                                                       acc[q], 0, 0, 0);
  };

  // Depth-2 pipeline over 24 chunks: iteration c does ISSUE(c+2), COMP(c),
  // then waits vmcnt(5) (chunk c+1 complete, c+2's 5 loads still in flight).
  ISSUE(0, b0); ISSUE(1, b1);
  WAITB(5);                                     // chunk 0 ready
#pragma unroll 1
  for (int c = 0; c < 21; c += 3) {             // c = 0..20 (7 triples)
    ISSUE(c + 2, b2); COMP(b0); WAITB(5);
    ISSUE(c + 3, b0); COMP(b1); WAITB(5);
    ISSUE(c + 4, b1); COMP(b2); WAITB(5);
  }
  ISSUE(23, b2); COMP(b0); WAITB(5);            // c = 21; chunk 22 ready
  COMP(b1);                                     // chunk 22
  WAITB(0);                                     // chunk 23 fully landed
  COMP(b2);                                     // chunk 23

#pragma unroll
  for (int q = 0; q < NP; ++q)
    __builtin_nontemporal_store(
        acc[q], (f32x4*)(pp + (size_t)(P0 + 4 * q) * 256 + lane * 4));
}

// Partial Gram via MFMA with async triple-buffered f32 LDS. Grid (27,16) x 256.
__global__ __launch_bounds__(256) void k_gram(const float* __restrict__ x,
                                              float* __restrict__ outsc) {
  __shared__ float lds[3 * 5120];   // 3 x [160][32] f32 = 60 KB
  const int bs = blockIdx.y, ch = blockIdx.x;
  const int t = threadIdx.x, w = t >> 6, lane = t & 63;
  const float* xb = x + (size_t)bs * D_ * N_ + (size_t)ch * NBC_;
  float* pp = outsc + (size_t)(ch * BS_ + bs) * (55 * 256);
  // Every wave executes the same barrier sequence (divergent roles OK).
  switch (w) {
    case 0:  gram_pipe<0, 14>(xb, lds, lds + 5120, lds + 10240, pp, 0, lane); break;
    case 1:  gram_pipe<1, 14>(xb, lds, lds + 5120, lds + 10240, pp, 1, lane); break;
    case 2:  gram_pipe<2, 14>(xb, lds, lds + 5120, lds + 10240, pp, 2, lane); break;
    default: gram_pipe<3, 13>(xb, lds, lds + 5120, lds + 10240, pp, 3, lane); break;
  }
}

// Reduce 27 partials (nontemporal reads), unscramble C/D layout, mirror.
// Grid (55,16). Also builds the rbfs dictionary R (fused former k_init).
__global__ __launch_bounds__(256) void k_gsum(const float* __restrict__ outsc,
                                              float* __restrict__ ws) {
  const int p = blockIdx.x, bs = blockIdx.y, s = threadIdx.x;
  const float* q = outsc + (size_t)bs * (55 * 256) + (size_t)p * 256 + s;
  float v = 0.f;
#pragma unroll
  for (int c = 0; c < KC_; ++c)
    v += __builtin_nontemporal_load(q + (size_t)c * ((size_t)BS_ * 55 * 256));
  const int l = s >> 2, r = s & 3;
  const int row = (l >> 4) * 4 + r, col = l & 15;
  const int gi = PI_[p] * 16 + row, gj = PJ_[p] * 16 + col;
  float* G = ws + OFF_G + (size_t)bs * (D_ * D_);
  G[gi * D_ + gj] = v;
  G[gj * D_ + gi] = v;

  // ---- fused R init (former k_init): first 280 block-worths cover 160*448 ----
  const int gid = (bs * 55 + p) * 256 + s;
  if (gid < D_ * RP_) {
    const int d = gid / RP_, j = gid % RP_;
    float rv;
    if (j == RP_ - 1) {
      rv = 0.f;                                  // pad column
    } else if (j == P2_ - 1) {
      rv = 1.f;
    } else {
      float sig; int colc;
      if (j < 160)      { sig = 1.f;  colc = j; }
      else if (j < 240) { sig = 2.f;  colc = 2 * (j - 160); }
      else if (j < 320) { sig = 4.f;  colc = 2 * (j - 240); }
      else if (j < 374) { sig = 6.f;  colc = 3 * (j - 320); }
      else if (j < 414) { sig = 8.f;  colc = 4 * (j - 374); }
      else              { sig = 10.f; colc = 5 * (j - 414); }
      float diff = (float)(d - colc);
      rv = expf(diff * diff * (-0.25f / (sig * sig)));
    }
    ws[OFF_R + gid] = rv;
  }
}

// All 4 NMF steps + final bp_f/s_f. One block per batch, 512 threads.
// R5: G cached in LDS (stride 164). R11: phase 1 wave-cooperative.
// R13: R hoisted to registers (140 VGPR/lane, rreg[rr][c] = R[20w+rr][64c+lane]).
// R15: phase 3 reuses rreg — nb[j]=sum_d R[d][j]*y[d] computed as 8 per-wave
// partials (280 FMA/lane, ZERO exps/loads) + LDS cross-wave reduce. Replaces
// 160 exp2f/thread/step (OCML multi-instr + quarter-rate trans pipe).
#define GLSTR 164
__global__ __launch_bounds__(512, 2) void k_iter(const float* __restrict__ bases0,
                                                 float* __restrict__ ws) {
  const int bs = blockIdx.x;
  const int t  = threadIdx.x;
  const int w  = t >> 6;
  const int lane = t & 63;
  __shared__ __align__(16) float basl[RP_];
  __shared__ __align__(16) float bpl[D_];
  __shared__ __align__(16) float yl[D_];
  __shared__ float redA[8], redB[8];
  __shared__ __align__(16) float nbp[8][RP_];      // 14 KB
  __shared__ __align__(16) float rbp[8][RP_];      // 14 KB
  __shared__ __align__(16) float gl[D_ * GLSTR];   // ~105 KB
  if (t < RP_) basl[t] = (t < P2_) ? bases0[bs * P2_ + t] : 0.f;

  // ---- R13: load this wave's R rows into registers (once) ----
  const float* rw = ws + OFF_R + (size_t)(20 * w) * RP_ + lane;
  float rreg[20][7];
#pragma unroll
  for (int rr = 0; rr < 20; ++rr)
#pragma unroll
    for (int c = 0; c < 7; ++c)
      rreg[rr][c] = rw[(size_t)rr * RP_ + 64 * c];

  // Preload G into LDS (overlaps the R register loads above).
  const float* G = ws + OFF_G + (size_t)bs * (D_ * D_);
  for (int i = t; i < D_ * 40; i += 512) {
    const int r = i / 40, k = i - r * 40;
    *(f32x4*)&gl[r * GLSTR + k * 4] = *(const f32x4*)(G + (size_t)r * D_ + k * 4);
  }
  __syncthreads();

  const float4* bpl4 = (const float4*)bpl;

  for (int step = 0; step < 5; ++step) {
    // ---- phase 1: bp = R @ bases (register R, wave-cooperative) ----
    {
      float bl[7];
#pragma unroll
      for (int c = 0; c < 7; ++c) bl[c] = basl[lane + 64 * c];
#pragma unroll
      for (int rr = 0; rr < 20; rr += 4) {
        float p0 = 0.f, p1 = 0.f, p2 = 0.f, p3 = 0.f;
#pragma unroll
        for (int c = 0; c < 7; ++c) {
          p0 = fmaf(rreg[rr][c],     bl[c], p0);
          p1 = fmaf(rreg[rr + 1][c], bl[c], p1);
          p2 = fmaf(rreg[rr + 2][c], bl[c], p2);
          p3 = fmaf(rreg[rr + 3][c], bl[c], p3);
        }
        p0 = wave_sum(p0); p1 = wave_sum(p1);
        p2 = wave_sum(p2); p3 = wave_sum(p3);
        if (lane == 0) {
          bpl[20 * w + rr]     = p0;
          bpl[20 * w + rr + 1] = p1;
          bpl[20 * w + rr + 2] = p2;
          bpl[20 * w + rr + 3] = p3;
        }
      }
    }
    __syncthreads();                       // bpl visible to all
    const float bpv = (t < D_) ? bpl[t] : 0.f;
    { float v = wave_sum(bpv * bpv);
      if ((t & 63) == 0) redA[w] = v; }
    __syncthreads();
    float s = 0.f;
#pragma unroll
    for (int i = 0; i < 8; ++i) s += redA[i];

    if (step == 4) {
      if (t < D_) ws[OFF_BPF + bs * D_ + t] = bpv;
      if (t == 0) ws[OFF_SF + bs] = 1.f / s;
      return;
    }

    // ---- phase 2: y = G @ bp (from LDS) ----
    float yv = 0.f;
    if (t < D_) {
      const float* gr = &gl[t * GLSTR];
#pragma unroll
      for (int k = 0; k < 40; ++k) {
        float4 gv = *(const float4*)(gr + 4 * k);
        yv = dot4(gv, bpl4[k], yv);
      }
      yl[t] = yv;
    }
    { float v = wave_sum((t < D_) ? bpv * yv : 0.f);
      if ((t & 63) == 0) redB[w] = v; }
    __syncthreads();
    float byp = 0.f;
#pragma unroll
    for (int i = 0; i < 8; ++i) byp += redB[i];

    // ---- phase 3 (R15): per-wave partials from rreg, LDS reduce ----
    // Wave w covers d in [20w, 20w+20): nb_part[j] = sum_rr rreg[rr][c]*yl[...]
    // for j = 64c+lane. yl/bpl reads are wave-uniform broadcasts (free).
#pragma unroll
    for (int c = 0; c < 7; ++c) {
      float nb = 0.f, rb = 0.f;
#pragma unroll
      for (int rr = 0; rr < 20; ++rr) {
        const float r = rreg[rr][c];
        nb = fmaf(r, yl[20 * w + rr],  nb);
        rb = fmaf(r, bpl[20 * w + rr], rb);
      }
      nbp[w][64 * c + lane] = nb;
      rbp[w][64 * c + lane] = rb;
    }
    __syncthreads();
    if (t < P2_) {
      float nb = 0.f, rb = 0.f;
#pragma unroll
      for (int i = 0; i < 8; ++i) { nb += nbp[i][t]; rb += rbp[i][t]; }
      const float c2 = byp / (s * s);
      basl[t] = basl[t] * (nb / s) / (rb * c2 + EPS_);
    }
    __syncthreads();
  }
}

// Pass A: cn[bs][n] = (x^T bp_f)*sf. Pure 212MB read stream. Grid (81,16)x256,
// 4 waves split d (40 rows each), 4KB LDS cross-wave reduce. cn stored into out
// row d=0 as scratch (overwritten with the true row 0 by k_out).
__global__ __launch_bounds__(256) void k_coef(const float* __restrict__ x,
                                              const float* __restrict__ ws,
                                              float* __restrict__ out) {
  __shared__ __align__(16) float bpl[D_];
  __shared__ __align__(16) float nsum[4][256];
  const int bs = blockIdx.y, cb = blockIdx.x;
  const int t = threadIdx.x, w = t >> 6, lane = t & 63;
  const int n0 = cb * 256;                 // 81 blocks * 256 cols = 20736 exactly

  if (t < D_) bpl[t] = ws[OFF_BPF + bs * D_ + t];
  __syncthreads();

  const float* xb = x + (size_t)bs * D_ * N_ + n0 + lane * 4;
  const int d0 = w * 40;
  float4 num = {0.f, 0.f, 0.f, 0.f};
#pragma unroll 8
  for (int k = 0; k < 40; ++k) {
    float4 v = *(const float4*)(xb + (size_t)(d0 + k) * N_);
    const float b = bpl[d0 + k];
    num.x = fmaf(v.x, b, num.x);
    num.y = fmaf(v.y, b, num.y);
    num.z = fmaf(v.z, b, num.z);
    num.w = fmaf(v.w, b, num.w);
  }
  *(float4*)&nsum[w][lane * 4] = num;
  __syncthreads();

  const float sf = ws[OFF_SF + bs];
  out[(size_t)bs * D_ * N_ + n0 + t] =
      (nsum[0][t] + nsum[1][t] + nsum[2][t] + nsum[3][t]) * sf;
}

// Pass B: out[d][n] = bp[d]*cn[n]. Pure 212MB write stream (nontemporal).
// cn read from out row 0 BEFORE a vmcnt(0)+barrier fence, then row 0 is
// overwritten with its true value like every other row.
__global__ __launch_bounds__(256) void k_out(const float* __restrict__ ws,
                                             float* __restrict__ out) {
  __shared__ __align__(16) float bpl[D_];
  const int bs = blockIdx.y, cb = blockIdx.x;
  const int t = threadIdx.x, w = t >> 6, lane = t & 63;
  const int n0 = cb * 256;

  float* ob = out + (size_t)bs * D_ * N_ + n0 + lane * 4;
  const f32x4 cn = *(const f32x4*)ob;      // row-0 scratch read (all 4 waves)
  if (t < D_) bpl[t] = ws[OFF_BPF + bs * D_ + t];
  // Ensure every wave's cn load has COMPLETED before any wave stores row 0.
  asm volatile("s_waitcnt vmcnt(0)" ::: "memory");
  __syncthreads();

  const int d0 = w * 40;
#pragma unroll 8
  for (int k = 0; k < 40; ++k) {
    const float b = bpl[d0 + k];
    f32x4 o;
    o[0] = b * cn[0]; o[1] = b * cn[1]; o[2] = b * cn[2]; o[3] = b * cn[3];
    __builtin_nontemporal_store(o, (f32x4*)(ob + (size_t)(d0 + k) * N_));
  }
}

extern "C" void kernel_launch(void* const* d_in, const int* in_sizes, int n_in,
                              void* d_out, int out_size, void* d_ws, size_t ws_size,
                              hipStream_t stream) {
  const float* x      = (const float*)d_in[0];   // (16,160,20736)
  const float* bases0 = (const float*)d_in[1];   // (16,447,1)
  float* out = (float*)d_out;                    // gram-partial scratch, then final output
  float* ws  = (float*)d_ws;                     // needs WS_FLOATS*4 ≈ 2.2 MB

  k_gram<<<dim3(KC_, BS_), 256, 0, stream>>>(x, out);
  k_gsum<<<dim3(55, BS_), 256, 0, stream>>>(out, ws);   // partials + fused R init
  k_iter<<<BS_, 512, 0, stream>>>(bases0, ws);
  k_coef<<<dim3(81, BS_), 256, 0, stream>>>(x, ws, out);
  k_out<<<dim3(81, BS_), 256, 0, stream>>>(ws, out);
}